// Round 7
// baseline (710.595 us; speedup 1.0000x reference)
//
#include <hip/hip_runtime.h>

#define NFEAT 128
#define NCLS  10
#define NCP   16    // padded class count
#define BROW  512   // rows per bucket
#define BINC  4096  // items per binning chunk

static inline size_t alignup(size_t x) { return (x + 255) & ~size_t(255); }

// bf16 helpers (bit-level, RNE)
__device__ __forceinline__ ushort f2bf(float f) {
  uint x = __float_as_uint(f);
  return (ushort)((x + 0x7fffu + ((x >> 16) & 1u)) >> 16);
}
__device__ __forceinline__ float bf2f(ushort u) {
  return __uint_as_float(((uint)u) << 16);
}

typedef short bf16x8 __attribute__((ext_vector_type(8)));
typedef float f32x4 __attribute__((ext_vector_type(4)));

// ---------------- CSR build (bucketed, write-amplification-free) ----------------

__global__ void zero_ints(int* __restrict__ p, int n) {
  int i = blockIdx.x * 256 + threadIdx.x;
  if (i < n) p[i] = 0;
}

__global__ __launch_bounds__(256) void bucket_hist(const int* __restrict__ dst,
                                                   int* __restrict__ bkt_cnt,
                                                   int e, int nbkt) {
  __shared__ int hist[256];
  for (int t = threadIdx.x; t < nbkt; t += 256) hist[t] = 0;
  __syncthreads();
  int i = blockIdx.x * 256 + threadIdx.x;
  int stride = gridDim.x * 256;
  for (; i < e; i += stride) atomicAdd(&hist[dst[i] >> 9], 1);
  __syncthreads();
  for (int t = threadIdx.x; t < nbkt; t += 256)
    if (hist[t]) atomicAdd(&bkt_cnt[t], hist[t]);
}

__global__ __launch_bounds__(256) void bkt_scan(const int* __restrict__ bkt_cnt,
                                                int* __restrict__ bkt_off,
                                                int* __restrict__ gfrontier,
                                                int n, int nbkt) {
  __shared__ int sbuf[256];
  const int t = threadIdx.x;
  int x = 0;
  if (t < nbkt) {
    int lo = t << 9;
    int nodes = n - lo; if (nodes > BROW) nodes = BROW;
    x = bkt_cnt[t] + nodes;
  }
  sbuf[t] = x;
  __syncthreads();
  for (int off = 1; off < 256; off <<= 1) {
    int v = (t >= off) ? sbuf[t - off] : 0;
    __syncthreads();
    sbuf[t] += v;
    __syncthreads();
  }
  if (t < nbkt) { bkt_off[t] = sbuf[t] - x; gfrontier[t] = sbuf[t] - x; }
  if (t == nbkt - 1) bkt_off[nbkt] = sbuf[t];
}

__global__ __launch_bounds__(256) void bin_items(const int* __restrict__ ei,
                                                 int nE, int total, int nbkt,
                                                 int* __restrict__ gfrontier,
                                                 int2* __restrict__ binned) {
  __shared__ int hist[256];
  __shared__ int loff[256];
  __shared__ int gbase[256];
  __shared__ int sbuf[256];
  __shared__ int2 st[BINC];
  const int t = threadIdx.x;
  const int chunk0 = blockIdx.x * BINC;
  for (int q = t; q < nbkt; q += 256) hist[q] = 0;
  __syncthreads();
  for (int j = t; j < BINC; j += 256) {
    int i = chunk0 + j;
    if (i < total) {
      int d = (i < nE) ? ei[nE + i] : (i - nE);
      atomicAdd(&hist[d >> 9], 1);
    }
  }
  __syncthreads();
  int x = (t < nbkt) ? hist[t] : 0;
  sbuf[t] = x;
  __syncthreads();
  for (int off = 1; off < 256; off <<= 1) {
    int v = (t >= off) ? sbuf[t - off] : 0;
    __syncthreads();
    sbuf[t] += v;
    __syncthreads();
  }
  loff[t] = sbuf[t] - x;
  gbase[t] = (t < nbkt && x > 0) ? atomicAdd(&gfrontier[t], x) : 0;
  __syncthreads();
  hist[t] = loff[t];
  __syncthreads();
  for (int j = t; j < BINC; j += 256) {
    int i = chunk0 + j;
    if (i < total) {
      int s, d;
      if (i < nE) { s = ei[i]; d = ei[nE + i]; }
      else        { s = i - nE; d = s; }
      int p = atomicAdd(&hist[d >> 9], 1);
      st[p] = make_int2(s, d);
    }
  }
  __syncthreads();
  int M = total - chunk0; if (M > BINC) M = BINC;
  for (int j = t; j < M; j += 256) {
    int2 it = st[j];
    int b = it.y >> 9;
    binned[gbase[b] + (j - loff[b])] = it;
  }
}

__global__ __launch_bounds__(512) void bucket_finalize(const int2* __restrict__ binned,
                                                       const int* __restrict__ bkt_off,
                                                       int* __restrict__ row_ptr,
                                                       float* __restrict__ dis,
                                                       int* __restrict__ ev,
                                                       int n, int nbkt) {
  __shared__ int hist[BROW];
  __shared__ int sbuf[BROW];
  __shared__ int pre[BROW];
  __shared__ int front[BROW];
  const int b = blockIdx.x;
  const int t = threadIdx.x;
  const int row0 = b << 9;
  const int beg = bkt_off[b], end = bkt_off[b + 1];
  hist[t] = 0; front[t] = 0;
  __syncthreads();
  for (int j = beg + t; j < end; j += BROW)
    atomicAdd(&hist[binned[j].y - row0], 1);
  __syncthreads();
  const int x = hist[t];
  const int v = row0 + t;
  if (v < n) dis[v] = rsqrtf((float)x);
  sbuf[t] = x;
  __syncthreads();
  for (int off = 1; off < BROW; off <<= 1) {
    int val = (t >= off) ? sbuf[t - off] : 0;
    __syncthreads();
    sbuf[t] += val;
    __syncthreads();
  }
  pre[t] = sbuf[t] - x;
  if (v < n) row_ptr[v] = beg + pre[t];
  if (b == nbkt - 1 && t == 0) row_ptr[n] = end;
  __syncthreads();
  for (int j = beg + t; j < end; j += BROW) {
    int2 it = binned[j];
    int dl = it.y - row0;
    int slot = atomicAdd(&front[dl], 1);
    ev[beg + pre[dl] + slot] = it.x;
  }
}

// ---------------- weight prep ----------------

__global__ __launch_bounds__(256) void fold_weights(const float* __restrict__ W3,
                                                    const float* __restrict__ Wl,
                                                    const float* __restrict__ b3,
                                                    const float* __restrict__ bl,
                                                    float* __restrict__ Wf,
                                                    float* __restrict__ bf) {
  int t = blockIdx.x * blockDim.x + threadIdx.x;
  if (t < NFEAT * NCP) {
    int r = t >> 4, c = t & 15;
    float s = 0.f;
    if (c < NCLS) {
      for (int k = 0; k < NFEAT; ++k) s += W3[r * NFEAT + k] * Wl[k * NCLS + c];
    }
    Wf[t] = s;
  }
  if (t < NCP) {
    float s = 0.f;
    if (t < NCLS) {
      s = bl[t];
      for (int k = 0; k < NFEAT; ++k) s += b3[k] * Wl[k * NCLS + t];
    }
    bf[t] = s;
  }
}

__global__ __launch_bounds__(256) void prep_w(const float* __restrict__ W,
                                              ushort* __restrict__ Wt) {
  int t = blockIdx.x * 256 + threadIdx.x;
  if (t < NFEAT * NFEAT) {
    int n = t >> 7, k = t & 127;
    Wt[n * NFEAT + k] = f2bf(W[k * NFEAT + n]);
  }
}

// ---- MFMA GEMM: CbS (sliced bf16 planes) = dis[r] * (A[r] @ W) ----
// SLICED=false: A is fp32 row-major. SLICED=true: A is sliced bf16 planes (AS).
// Sliced layout: plane p (16 feats), element (p*pstride + v*16 + f), f in [0,16).

template<bool SLICED>
__global__ __launch_bounds__(256) void gemm_mfma(const float* __restrict__ A,
                                                 const ushort* __restrict__ AS,
                                                 size_t pstride,
                                                 const ushort* __restrict__ Wt,
                                                 const float* __restrict__ dis,
                                                 ushort* __restrict__ CbS, int nrows) {
  __shared__ __align__(16) ushort Asm[64 * NFEAT];   // 16 KB
  const int tid = threadIdx.x;
  const int row0 = blockIdx.x * 64;
  {
    const int m = tid >> 2;
    const int kc = (tid & 3) * 32;
    const int gr = row0 + m;
    int4 u[4];
    if (SLICED) {
      if (gr < nrows) {
        const int p0 = kc >> 4;
        const ushort* pl0 = AS + (size_t)p0 * pstride + (size_t)gr * 16;
        const ushort* pl1 = pl0 + pstride;
        u[0] = *(const int4*)pl0;
        u[1] = *(const int4*)(pl0 + 8);
        u[2] = *(const int4*)pl1;
        u[3] = *(const int4*)(pl1 + 8);
      } else {
        u[0] = u[1] = u[2] = u[3] = make_int4(0, 0, 0, 0);
      }
    } else {
      float4 f[8];
      if (gr < nrows) {
        #pragma unroll
        for (int q = 0; q < 8; ++q)
          f[q] = *(const float4*)&A[(size_t)gr * NFEAT + kc + q * 4];
      } else {
        #pragma unroll
        for (int q = 0; q < 8; ++q) f[q] = make_float4(0.f, 0.f, 0.f, 0.f);
      }
      #pragma unroll
      for (int q = 0; q < 4; ++q) {
        union { ushort us[8]; int4 v; } pk;
        const float* fp = (const float*)&f[q * 2];
        #pragma unroll
        for (int j = 0; j < 8; ++j) pk.us[j] = f2bf(fp[j]);
        u[q] = pk.v;
      }
    }
    #pragma unroll
    for (int q = 0; q < 4; ++q) {
      int byte = (m * 256 + (kc + q * 8) * 2) ^ ((m & 7) << 4);
      *(int4*)((char*)Asm + byte) = u[q];
    }
  }
  __syncthreads();
  const int wave = tid >> 6;
  const int lane = tid & 63;
  const int m0 = wave * 16;
  bf16x8 afr[4];
  #pragma unroll
  for (int ks = 0; ks < 4; ++ks) {
    int m = m0 + (lane & 15);
    int kk = ks * 32 + (lane >> 4) * 8;
    int byte = (m * 256 + kk * 2) ^ ((m & 7) << 4);
    afr[ks] = *(const bf16x8*)((const char*)Asm + byte);
  }
  f32x4 acc[8];
  #pragma unroll
  for (int c = 0; c < 8; ++c) acc[c] = (f32x4){0.f, 0.f, 0.f, 0.f};
  #pragma unroll
  for (int c = 0; c < 8; ++c) {
    #pragma unroll
    for (int ks = 0; ks < 4; ++ks) {
      int n = c * 16 + (lane & 15);
      int kk = ks * 32 + (lane >> 4) * 8;
      bf16x8 bfr = *(const bf16x8*)&Wt[n * NFEAT + kk];
      acc[c] = __builtin_amdgcn_mfma_f32_16x16x32_bf16(afr[ks], bfr, acc[c], 0, 0, 0);
    }
  }
  const int gr_base = row0 + m0 + (lane >> 4) * 4;
  float dr[4];
  #pragma unroll
  for (int r = 0; r < 4; ++r)
    dr[r] = (gr_base + r < nrows) ? dis[gr_base + r] : 0.f;
  #pragma unroll
  for (int c = 0; c < 8; ++c) {
    ushort* plane = CbS + (size_t)c * pstride;
    #pragma unroll
    for (int r = 0; r < 4; ++r) {
      int gr = gr_base + r;
      if (gr < nrows)
        plane[(size_t)gr * 16 + (lane & 15)] = f2bf(acc[c][r] * dr[r]);
    }
  }
}

// ---- sliced aggregation: block = (plane s = bid&7 -> XCD s, 16 nodes) ----
// outS[v] = relu?(dis[v] * sum_src plane[src] + bias_slice)

__global__ __launch_bounds__(256) void aggregate(const ushort* __restrict__ hbS,
                                                 const int* __restrict__ row_ptr,
                                                 const int* __restrict__ ev,
                                                 const float* __restrict__ dis,
                                                 const float* __restrict__ bias,
                                                 ushort* __restrict__ outS,
                                                 size_t pstride, int relu, int n) {
  const int s = blockIdx.x & 7;
  const int chunk = blockIdx.x >> 3;
  const int wave = threadIdx.x >> 6;
  const int lane = threadIdx.x & 63;
  const int f4 = lane & 3;        // 4 feats per lane (ushort4)
  const int ep = lane >> 2;       // 16 edges in flight
  const ushort* plane = hbS + (size_t)s * pstride;
  ushort* oplane = outS + (size_t)s * pstride;
  const float4 bs = *(const float4*)&bias[s * 16 + f4 * 4];
  #pragma unroll
  for (int q = 0; q < 4; ++q) {
    const int v = chunk * 16 + wave * 4 + q;
    if (v >= n) return;
    const int beg = row_ptr[v], end = row_ptr[v + 1];
    float4 acc = make_float4(0.f, 0.f, 0.f, 0.f);
    for (int e = beg + ep; e < end; e += 16) {
      int src = __builtin_nontemporal_load(&ev[e]);
      ushort4 q4 = *(const ushort4*)&plane[(size_t)src * 16 + f4 * 4];
      acc.x += bf2f(q4.x); acc.y += bf2f(q4.y);
      acc.z += bf2f(q4.z); acc.w += bf2f(q4.w);
    }
    #pragma unroll
    for (int off = 4; off <= 32; off <<= 1) {
      acc.x += __shfl_xor(acc.x, off);
      acc.y += __shfl_xor(acc.y, off);
      acc.z += __shfl_xor(acc.z, off);
      acc.w += __shfl_xor(acc.w, off);
    }
    if (ep == 0) {
      const float dv = dis[v];
      float4 r;
      r.x = fmaf(acc.x, dv, bs.x);
      r.y = fmaf(acc.y, dv, bs.y);
      r.z = fmaf(acc.z, dv, bs.z);
      r.w = fmaf(acc.w, dv, bs.w);
      if (relu) {
        r.x = fmaxf(r.x, 0.f); r.y = fmaxf(r.y, 0.f);
        r.z = fmaxf(r.z, 0.f); r.w = fmaxf(r.w, 0.f);
      }
      union { ushort us[4]; uint2 q2; } pk;
      pk.us[0] = f2bf(r.x); pk.us[1] = f2bf(r.y);
      pk.us[2] = f2bf(r.z); pk.us[3] = f2bf(r.w);
      *(uint2*)&oplane[(size_t)v * 16 + f4 * 4] = pk.q2;
    }
  }
}

// ---- thin GEMM: G[v][16](fp32) = dis[v] * (AS[v] @ Wf), AS sliced bf16 ----

__global__ __launch_bounds__(256) void gemm_small(const ushort* __restrict__ AS,
                                                  size_t pstride,
                                                  const float* __restrict__ Wf,
                                                  const float* __restrict__ dis,
                                                  float* __restrict__ G, int n) {
  __shared__ float Ws[NFEAT * NCP];  // 8 KB
  for (int i = threadIdx.x; i < NFEAT * NCP; i += 256) Ws[i] = Wf[i];
  __syncthreads();
  const int v = blockIdx.x * 256 + threadIdx.x;
  if (v >= n) return;
  float acc[NCP];
  #pragma unroll
  for (int c = 0; c < NCP; ++c) acc[c] = 0.f;
  #pragma unroll
  for (int p = 0; p < 8; ++p) {
    union { ushort us[16]; int4 q[2]; } a;
    const ushort* pl = AS + (size_t)p * pstride + (size_t)v * 16;
    a.q[0] = *(const int4*)pl;
    a.q[1] = *(const int4*)(pl + 8);
    #pragma unroll
    for (int j = 0; j < 16; ++j) {
      float av = bf2f(a.us[j]);
      int k = p * 16 + j;
      #pragma unroll
      for (int cq = 0; cq < NCP; cq += 4) {
        float4 w = *(const float4*)&Ws[k * NCP + cq];
        acc[cq + 0] += av * w.x;
        acc[cq + 1] += av * w.y;
        acc[cq + 2] += av * w.z;
        acc[cq + 3] += av * w.w;
      }
    }
  }
  const float dv = dis[v];
  #pragma unroll
  for (int cq = 0; cq < NCP; cq += 4)
    *(float4*)&G[(size_t)v * NCP + cq] =
        make_float4(acc[cq] * dv, acc[cq + 1] * dv, acc[cq + 2] * dv, acc[cq + 3] * dv);
}

// ---------------- fused aggregation (16 feats) + bias + log_softmax ----------------

__global__ __launch_bounds__(256) void agg_logits(const float* __restrict__ G,
                                                  const int* __restrict__ row_ptr,
                                                  const int* __restrict__ ev,
                                                  const float* __restrict__ dis,
                                                  const float* __restrict__ bf,
                                                  float* __restrict__ out, int n) {
  const int wave = threadIdx.x >> 6;
  const int lane = threadIdx.x & 63;
  const int v = blockIdx.x * 4 + wave;
  if (v >= n) return;
  const int beg = row_ptr[v], end = row_ptr[v + 1];
  const int g = lane >> 4;           // 4 edge groups
  const int f = lane & 15;           // feature (class) index
  float acc = 0.f;
  int e = beg + g;
  for (; e + 4 < end; e += 8) {
    int s0 = ev[e];
    int s1 = ev[e + 4];
    acc += G[(size_t)s0 * NCP + f] + G[(size_t)s1 * NCP + f];
  }
  for (; e < end; e += 4) {
    acc += G[(size_t)ev[e] * NCP + f];
  }
  acc += __shfl_xor(acc, 16);
  acc += __shfl_xor(acc, 32);
  float logit = dis[v] * acc + bf[f];
  float pv = (f < NCLS) ? logit : -INFINITY;
  float m = pv;
  #pragma unroll
  for (int s = 8; s >= 1; s >>= 1) m = fmaxf(m, __shfl_xor(m, s));
  float ex = (f < NCLS) ? expf(logit - m) : 0.f;
  float ssum = ex;
  #pragma unroll
  for (int s = 8; s >= 1; s >>= 1) ssum += __shfl_xor(ssum, s);
  float lse = m + logf(ssum);
  if (g == 0 && f < NCLS) out[(size_t)v * NCLS + f] = logit - lse;
}

// ---------------- launcher ----------------

extern "C" void kernel_launch(void* const* d_in, const int* in_sizes, int n_in,
                              void* d_out, int out_size, void* d_ws, size_t ws_size,
                              hipStream_t stream) {
  const float* x  = (const float*)d_in[0];
  const int*   ei = (const int*)d_in[1];
  const float* W1 = (const float*)d_in[2];
  const float* b1 = (const float*)d_in[3];
  const float* W2 = (const float*)d_in[4];
  const float* b2 = (const float*)d_in[5];
  const float* W3 = (const float*)d_in[6];
  const float* b3 = (const float*)d_in[7];
  const float* Wl = (const float*)d_in[8];
  const float* bl = (const float*)d_in[9];
  float* out = (float*)d_out;

  const int nN = in_sizes[0] / NFEAT;   // 100000
  const int nE = in_sizes[1] / 2;       // 1600000
  const int total = nN + nE;
  const int nbkt = (nN + BROW - 1) >> 9;          // 196
  const int nbBin = (total + BINC - 1) / BINC;
  const size_t pstride = (size_t)nN * 16;         // elements per plane

  char* ws = (char*)d_ws;
  int*    bkt_cnt = (int*)ws;     ws += alignup(256 * 4);
  int*    bkt_off = (int*)ws;     ws += alignup(257 * 4);
  int*    gfront  = (int*)ws;     ws += alignup(256 * 4);
  int*    row_ptr = (int*)ws;     ws += alignup((size_t)(nN + 1) * 4);
  float*  dis     = (float*)ws;   ws += alignup((size_t)nN * 4);
  float*  Wf      = (float*)ws;   ws += alignup((size_t)NFEAT * NCP * 4);
  float*  bfv     = (float*)ws;   ws += alignup((size_t)NCP * 4);
  ushort* Wt1     = (ushort*)ws;  ws += alignup((size_t)NFEAT * NFEAT * 2);
  ushort* Wt2     = (ushort*)ws;  ws += alignup((size_t)NFEAT * NFEAT * 2);
  int2*   binned  = (int2*)ws;    ws += alignup((size_t)total * 8);
  int*    ev      = (int*)ws;     ws += alignup((size_t)total * 4);
  ushort* hbS     = (ushort*)ws;  ws += alignup((size_t)nN * NFEAT * 2);  // sliced bf16
  ushort* aggS    = (ushort*)ws;  ws += alignup((size_t)nN * NFEAT * 2);  // sliced bf16
  float*  G       = (float*)ws;   ws += alignup((size_t)nN * NCP * 4);

  // ---- CSR build
  zero_ints<<<1, 256, 0, stream>>>(bkt_cnt, nbkt);
  bucket_hist<<<512, 256, 0, stream>>>(ei + nE, bkt_cnt, nE, nbkt);
  bkt_scan<<<1, 256, 0, stream>>>(bkt_cnt, bkt_off, gfront, nN, nbkt);
  bin_items<<<nbBin, 256, 0, stream>>>(ei, nE, total, nbkt, gfront, binned);
  bucket_finalize<<<nbkt, BROW, 0, stream>>>(binned, bkt_off, row_ptr, dis, ev, nN, nbkt);

  // ---- weight prep
  fold_weights<<<8, 256, 0, stream>>>(W3, Wl, b3, bl, Wf, bfv);
  prep_w<<<64, 256, 0, stream>>>(W1, Wt1);
  prep_w<<<64, 256, 0, stream>>>(W2, Wt2);

  const int gemm_grid = (nN + 63) / 64;
  const int agg_grid = ((nN + 15) / 16) * 8;      // plane = bid & 7 -> XCD affinity
  const int node_grid = (nN + 3) / 4;

  // layer 1
  gemm_mfma<false><<<gemm_grid, 256, 0, stream>>>(x, nullptr, pstride, Wt1, dis, hbS, nN);
  aggregate<<<agg_grid, 256, 0, stream>>>(hbS, row_ptr, ev, dis, b1, aggS, pstride, 1, nN);
  // layer 2
  gemm_mfma<true><<<gemm_grid, 256, 0, stream>>>(nullptr, aggS, pstride, Wt2, dis, hbS, nN);
  aggregate<<<agg_grid, 256, 0, stream>>>(hbS, row_ptr, ev, dis, b2, aggS, pstride, 1, nN);
  // layer 3 folded with classifier
  gemm_small<<<(nN + 255) / 256, 256, 0, stream>>>(aggS, pstride, Wf, dis, G, nN);
  agg_logits<<<node_grid, 256, 0, stream>>>(G, row_ptr, ev, dis, bfv, out, nN);
}

// Round 8
// 400.110 us; speedup vs baseline: 1.7760x; 1.7760x over previous
//
#include <hip/hip_runtime.h>

#define NFEAT 128
#define NCLS  10
#define NCP   16    // padded class count
#define BROW  512   // rows per bucket
#define BINC  4096  // items per binning chunk

static inline size_t alignup(size_t x) { return (x + 255) & ~size_t(255); }

// bf16 helpers (bit-level, RNE)
__device__ __forceinline__ ushort f2bf(float f) {
  uint x = __float_as_uint(f);
  return (ushort)((x + 0x7fffu + ((x >> 16) & 1u)) >> 16);
}
__device__ __forceinline__ float bf2f(ushort u) {
  return __uint_as_float(((uint)u) << 16);
}

typedef short bf16x8 __attribute__((ext_vector_type(8)));
typedef float f32x4 __attribute__((ext_vector_type(4)));

// ---------------- CSR build (bucketed, write-amplification-free) ----------------

__global__ void zero_ints(int* __restrict__ p, int n) {
  int i = blockIdx.x * 256 + threadIdx.x;
  if (i < n) p[i] = 0;
}

__global__ __launch_bounds__(256) void bucket_hist(const int* __restrict__ dst,
                                                   int* __restrict__ bkt_cnt,
                                                   int e, int nbkt) {
  __shared__ int hist[256];
  for (int t = threadIdx.x; t < nbkt; t += 256) hist[t] = 0;
  __syncthreads();
  int i = blockIdx.x * 256 + threadIdx.x;
  int stride = gridDim.x * 256;
  for (; i < e; i += stride) atomicAdd(&hist[dst[i] >> 9], 1);
  __syncthreads();
  for (int t = threadIdx.x; t < nbkt; t += 256)
    if (hist[t]) atomicAdd(&bkt_cnt[t], hist[t]);
}

__global__ __launch_bounds__(256) void bkt_scan(const int* __restrict__ bkt_cnt,
                                                int* __restrict__ bkt_off,
                                                int* __restrict__ gfrontier,
                                                int n, int nbkt) {
  __shared__ int sbuf[256];
  const int t = threadIdx.x;
  int x = 0;
  if (t < nbkt) {
    int lo = t << 9;
    int nodes = n - lo; if (nodes > BROW) nodes = BROW;
    x = bkt_cnt[t] + nodes;
  }
  sbuf[t] = x;
  __syncthreads();
  for (int off = 1; off < 256; off <<= 1) {
    int v = (t >= off) ? sbuf[t - off] : 0;
    __syncthreads();
    sbuf[t] += v;
    __syncthreads();
  }
  if (t < nbkt) { bkt_off[t] = sbuf[t] - x; gfrontier[t] = sbuf[t] - x; }
  if (t == nbkt - 1) bkt_off[nbkt] = sbuf[t];
}

__global__ __launch_bounds__(256) void bin_items(const int* __restrict__ ei,
                                                 int nE, int total, int nbkt,
                                                 int* __restrict__ gfrontier,
                                                 int2* __restrict__ binned) {
  __shared__ int hist[256];
  __shared__ int loff[256];
  __shared__ int gbase[256];
  __shared__ int sbuf[256];
  __shared__ int2 st[BINC];
  const int t = threadIdx.x;
  const int chunk0 = blockIdx.x * BINC;
  for (int q = t; q < nbkt; q += 256) hist[q] = 0;
  __syncthreads();
  for (int j = t; j < BINC; j += 256) {
    int i = chunk0 + j;
    if (i < total) {
      int d = (i < nE) ? ei[nE + i] : (i - nE);
      atomicAdd(&hist[d >> 9], 1);
    }
  }
  __syncthreads();
  int x = (t < nbkt) ? hist[t] : 0;
  sbuf[t] = x;
  __syncthreads();
  for (int off = 1; off < 256; off <<= 1) {
    int v = (t >= off) ? sbuf[t - off] : 0;
    __syncthreads();
    sbuf[t] += v;
    __syncthreads();
  }
  loff[t] = sbuf[t] - x;
  gbase[t] = (t < nbkt && x > 0) ? atomicAdd(&gfrontier[t], x) : 0;
  __syncthreads();
  hist[t] = loff[t];
  __syncthreads();
  for (int j = t; j < BINC; j += 256) {
    int i = chunk0 + j;
    if (i < total) {
      int s, d;
      if (i < nE) { s = ei[i]; d = ei[nE + i]; }
      else        { s = i - nE; d = s; }
      int p = atomicAdd(&hist[d >> 9], 1);
      st[p] = make_int2(s, d);
    }
  }
  __syncthreads();
  int M = total - chunk0; if (M > BINC) M = BINC;
  for (int j = t; j < M; j += 256) {
    int2 it = st[j];
    int b = it.y >> 9;
    binned[gbase[b] + (j - loff[b])] = it;
  }
}

__global__ __launch_bounds__(512) void bucket_finalize(const int2* __restrict__ binned,
                                                       const int* __restrict__ bkt_off,
                                                       int* __restrict__ row_ptr,
                                                       float* __restrict__ dis,
                                                       int* __restrict__ ev,
                                                       int n, int nbkt) {
  __shared__ int hist[BROW];
  __shared__ int sbuf[BROW];
  __shared__ int pre[BROW];
  __shared__ int front[BROW];
  const int b = blockIdx.x;
  const int t = threadIdx.x;
  const int row0 = b << 9;
  const int beg = bkt_off[b], end = bkt_off[b + 1];
  hist[t] = 0; front[t] = 0;
  __syncthreads();
  for (int j = beg + t; j < end; j += BROW)
    atomicAdd(&hist[binned[j].y - row0], 1);
  __syncthreads();
  const int x = hist[t];
  const int v = row0 + t;
  if (v < n) dis[v] = rsqrtf((float)x);
  sbuf[t] = x;
  __syncthreads();
  for (int off = 1; off < BROW; off <<= 1) {
    int val = (t >= off) ? sbuf[t - off] : 0;
    __syncthreads();
    sbuf[t] += val;
    __syncthreads();
  }
  pre[t] = sbuf[t] - x;
  if (v < n) row_ptr[v] = beg + pre[t];
  if (b == nbkt - 1 && t == 0) row_ptr[n] = end;
  __syncthreads();
  for (int j = beg + t; j < end; j += BROW) {
    int2 it = binned[j];
    int dl = it.y - row0;
    int slot = atomicAdd(&front[dl], 1);
    ev[beg + pre[dl] + slot] = it.x;
  }
}

// ---------------- weight prep ----------------

__global__ __launch_bounds__(256) void fold_weights(const float* __restrict__ W3,
                                                    const float* __restrict__ Wl,
                                                    const float* __restrict__ b3,
                                                    const float* __restrict__ bl,
                                                    float* __restrict__ Wf,
                                                    float* __restrict__ bf) {
  int t = blockIdx.x * blockDim.x + threadIdx.x;
  if (t < NFEAT * NCP) {
    int r = t >> 4, c = t & 15;
    float s = 0.f;
    if (c < NCLS) {
      for (int k = 0; k < NFEAT; ++k) s += W3[r * NFEAT + k] * Wl[k * NCLS + c];
    }
    Wf[t] = s;
  }
  if (t < NCP) {
    float s = 0.f;
    if (t < NCLS) {
      s = bl[t];
      for (int k = 0; k < NFEAT; ++k) s += b3[k] * Wl[k * NCLS + t];
    }
    bf[t] = s;
  }
}

__global__ __launch_bounds__(256) void prep_w(const float* __restrict__ W,
                                              ushort* __restrict__ Wt) {
  int t = blockIdx.x * 256 + threadIdx.x;
  if (t < NFEAT * NFEAT) {
    int n = t >> 7, k = t & 127;
    Wt[n * NFEAT + k] = f2bf(W[k * NFEAT + n]);
  }
}

// ---- MFMA GEMM: Cb[r](bf16 row-major) = dis[r] * (A[r] @ W) ----
// BF16IN=false: A fp32 row-major. BF16IN=true: Ab bf16 row-major.

template<bool BF16IN>
__global__ __launch_bounds__(256) void gemm_mfma(const float* __restrict__ A,
                                                 const ushort* __restrict__ Ab,
                                                 const ushort* __restrict__ Wt,
                                                 const float* __restrict__ dis,
                                                 ushort* __restrict__ Cb, int nrows) {
  __shared__ __align__(16) ushort Asm[64 * NFEAT];   // 16 KB
  const int tid = threadIdx.x;
  const int row0 = blockIdx.x * 64;
  {
    const int m = tid >> 2;
    const int kc = (tid & 3) * 32;
    const int gr = row0 + m;
    int4 u[4];
    if (BF16IN) {
      if (gr < nrows) {
        const ushort* p = Ab + (size_t)gr * NFEAT + kc;
        u[0] = *(const int4*)(p + 0);
        u[1] = *(const int4*)(p + 8);
        u[2] = *(const int4*)(p + 16);
        u[3] = *(const int4*)(p + 24);
      } else {
        u[0] = u[1] = u[2] = u[3] = make_int4(0, 0, 0, 0);
      }
    } else {
      float4 f[8];
      if (gr < nrows) {
        #pragma unroll
        for (int q = 0; q < 8; ++q)
          f[q] = *(const float4*)&A[(size_t)gr * NFEAT + kc + q * 4];
      } else {
        #pragma unroll
        for (int q = 0; q < 8; ++q) f[q] = make_float4(0.f, 0.f, 0.f, 0.f);
      }
      #pragma unroll
      for (int q = 0; q < 4; ++q) {
        union { ushort us[8]; int4 v; } pk;
        const float* fp = (const float*)&f[q * 2];
        #pragma unroll
        for (int j = 0; j < 8; ++j) pk.us[j] = f2bf(fp[j]);
        u[q] = pk.v;
      }
    }
    #pragma unroll
    for (int q = 0; q < 4; ++q) {
      int byte = (m * 256 + (kc + q * 8) * 2) ^ ((m & 7) << 4);
      *(int4*)((char*)Asm + byte) = u[q];
    }
  }
  __syncthreads();
  const int wave = tid >> 6;
  const int lane = tid & 63;
  const int m0 = wave * 16;
  bf16x8 afr[4];
  #pragma unroll
  for (int ks = 0; ks < 4; ++ks) {
    int m = m0 + (lane & 15);
    int kk = ks * 32 + (lane >> 4) * 8;
    int byte = (m * 256 + kk * 2) ^ ((m & 7) << 4);
    afr[ks] = *(const bf16x8*)((const char*)Asm + byte);
  }
  f32x4 acc[8];
  #pragma unroll
  for (int c = 0; c < 8; ++c) acc[c] = (f32x4){0.f, 0.f, 0.f, 0.f};
  #pragma unroll
  for (int c = 0; c < 8; ++c) {
    #pragma unroll
    for (int ks = 0; ks < 4; ++ks) {
      int n = c * 16 + (lane & 15);
      int kk = ks * 32 + (lane >> 4) * 8;
      bf16x8 bfr = *(const bf16x8*)&Wt[n * NFEAT + kk];
      acc[c] = __builtin_amdgcn_mfma_f32_16x16x32_bf16(afr[ks], bfr, acc[c], 0, 0, 0);
    }
  }
  const int gr_base = row0 + m0 + (lane >> 4) * 4;
  float dr[4];
  #pragma unroll
  for (int r = 0; r < 4; ++r)
    dr[r] = (gr_base + r < nrows) ? dis[gr_base + r] : 0.f;
  #pragma unroll
  for (int c = 0; c < 8; ++c) {
    #pragma unroll
    for (int r = 0; r < 4; ++r) {
      int gr = gr_base + r;
      if (gr < nrows)
        Cb[(size_t)gr * NFEAT + c * 16 + (lane & 15)] = f2bf(acc[c][r] * dr[r]);
    }
  }
}

// ------- sparse aggregation: outb[v] = bf16(relu?(dis[v]*Σ h'[src] + bias)) -------
// half-wave ushort4; 8 edges per half unrolled -> 16 gathers in flight per wave

__global__ __launch_bounds__(256) void aggregate(const ushort* __restrict__ hw,
                                                 const int* __restrict__ row_ptr,
                                                 const int* __restrict__ ev,
                                                 const float* __restrict__ dis,
                                                 const float* __restrict__ bias,
                                                 ushort* __restrict__ outb,
                                                 int relu, int n) {
  const int wave = threadIdx.x >> 6;
  const int lane = threadIdx.x & 63;
  const int v = blockIdx.x * 4 + wave;
  if (v >= n) return;
  const int beg = row_ptr[v], end = row_ptr[v + 1];
  const int half = lane >> 5;        // 0/1: edge parity handled by this half-wave
  const int hl = lane & 31;          // feature group: feats hl*4 .. hl*4+3
  float4 acc = make_float4(0.f, 0.f, 0.f, 0.f);
  int e = beg + half;
  for (; e + 14 < end; e += 16) {    // 8 edges per half per iter -> 16 gathers in flight
    int s[8];
    #pragma unroll
    for (int j = 0; j < 8; ++j) s[j] = __builtin_nontemporal_load(&ev[e + 2 * j]);
    ushort4 q[8];
    #pragma unroll
    for (int j = 0; j < 8; ++j)
      q[j] = *(const ushort4*)&hw[(size_t)s[j] * NFEAT + hl * 4];
    #pragma unroll
    for (int j = 0; j < 8; ++j) {
      acc.x += bf2f(q[j].x); acc.y += bf2f(q[j].y);
      acc.z += bf2f(q[j].z); acc.w += bf2f(q[j].w);
    }
  }
  for (; e < end; e += 2) {
    int s = __builtin_nontemporal_load(&ev[e]);
    ushort4 q = *(const ushort4*)&hw[(size_t)s * NFEAT + hl * 4];
    acc.x += bf2f(q.x); acc.y += bf2f(q.y);
    acc.z += bf2f(q.z); acc.w += bf2f(q.w);
  }
  acc.x += __shfl_xor(acc.x, 32);
  acc.y += __shfl_xor(acc.y, 32);
  acc.z += __shfl_xor(acc.z, 32);
  acc.w += __shfl_xor(acc.w, 32);
  if (half == 0) {
    float dv = dis[v];
    float4 b = *(const float4*)&bias[hl * 4];
    acc.x = fmaf(acc.x, dv, b.x); acc.y = fmaf(acc.y, dv, b.y);
    acc.z = fmaf(acc.z, dv, b.z); acc.w = fmaf(acc.w, dv, b.w);
    if (relu) {
      acc.x = fmaxf(acc.x, 0.f); acc.y = fmaxf(acc.y, 0.f);
      acc.z = fmaxf(acc.z, 0.f); acc.w = fmaxf(acc.w, 0.f);
    }
    union { ushort us[4]; uint2 q2; } pk;
    pk.us[0] = f2bf(acc.x); pk.us[1] = f2bf(acc.y);
    pk.us[2] = f2bf(acc.z); pk.us[3] = f2bf(acc.w);
    *(uint2*)&outb[(size_t)v * NFEAT + hl * 4] = pk.q2;
  }
}

// ---- thin GEMM: G[v][16](fp32) = dis[v] * (Ab[v] @ Wf), Ab bf16 row-major ----

__global__ __launch_bounds__(256) void gemm_small(const ushort* __restrict__ Ab,
                                                  const float* __restrict__ Wf,
                                                  const float* __restrict__ dis,
                                                  float* __restrict__ G, int n) {
  __shared__ float Ws[NFEAT * NCP];  // 8 KB
  for (int i = threadIdx.x; i < NFEAT * NCP; i += 256) Ws[i] = Wf[i];
  __syncthreads();
  const int v = blockIdx.x * 256 + threadIdx.x;
  if (v >= n) return;
  float acc[NCP];
  #pragma unroll
  for (int c = 0; c < NCP; ++c) acc[c] = 0.f;
  #pragma unroll
  for (int p = 0; p < 8; ++p) {
    union { ushort us[16]; int4 q[2]; } a;
    const ushort* pl = Ab + (size_t)v * NFEAT + p * 16;
    a.q[0] = *(const int4*)pl;
    a.q[1] = *(const int4*)(pl + 8);
    #pragma unroll
    for (int j = 0; j < 16; ++j) {
      float av = bf2f(a.us[j]);
      int k = p * 16 + j;
      #pragma unroll
      for (int cq = 0; cq < NCP; cq += 4) {
        float4 w = *(const float4*)&Ws[k * NCP + cq];
        acc[cq + 0] += av * w.x;
        acc[cq + 1] += av * w.y;
        acc[cq + 2] += av * w.z;
        acc[cq + 3] += av * w.w;
      }
    }
  }
  const float dv = dis[v];
  #pragma unroll
  for (int cq = 0; cq < NCP; cq += 4)
    *(float4*)&G[(size_t)v * NCP + cq] =
        make_float4(acc[cq] * dv, acc[cq + 1] * dv, acc[cq + 2] * dv, acc[cq + 3] * dv);
}

// ---------------- fused aggregation (16 feats) + bias + log_softmax ----------------

__global__ __launch_bounds__(256) void agg_logits(const float* __restrict__ G,
                                                  const int* __restrict__ row_ptr,
                                                  const int* __restrict__ ev,
                                                  const float* __restrict__ dis,
                                                  const float* __restrict__ bf,
                                                  float* __restrict__ out, int n) {
  const int wave = threadIdx.x >> 6;
  const int lane = threadIdx.x & 63;
  const int v = blockIdx.x * 4 + wave;
  if (v >= n) return;
  const int beg = row_ptr[v], end = row_ptr[v + 1];
  const int g = lane >> 4;           // 4 edge groups
  const int f = lane & 15;           // feature (class) index
  float acc = 0.f;
  int e = beg + g;
  for (; e + 4 < end; e += 8) {
    int s0 = ev[e];
    int s1 = ev[e + 4];
    acc += G[(size_t)s0 * NCP + f] + G[(size_t)s1 * NCP + f];
  }
  for (; e < end; e += 4) {
    acc += G[(size_t)ev[e] * NCP + f];
  }
  acc += __shfl_xor(acc, 16);
  acc += __shfl_xor(acc, 32);
  float logit = dis[v] * acc + bf[f];
  float pv = (f < NCLS) ? logit : -INFINITY;
  float m = pv;
  #pragma unroll
  for (int s = 8; s >= 1; s >>= 1) m = fmaxf(m, __shfl_xor(m, s));
  float ex = (f < NCLS) ? expf(logit - m) : 0.f;
  float ssum = ex;
  #pragma unroll
  for (int s = 8; s >= 1; s >>= 1) ssum += __shfl_xor(ssum, s);
  float lse = m + logf(ssum);
  if (g == 0 && f < NCLS) out[(size_t)v * NCLS + f] = logit - lse;
}

// ---------------- launcher ----------------

extern "C" void kernel_launch(void* const* d_in, const int* in_sizes, int n_in,
                              void* d_out, int out_size, void* d_ws, size_t ws_size,
                              hipStream_t stream) {
  const float* x  = (const float*)d_in[0];
  const int*   ei = (const int*)d_in[1];
  const float* W1 = (const float*)d_in[2];
  const float* b1 = (const float*)d_in[3];
  const float* W2 = (const float*)d_in[4];
  const float* b2 = (const float*)d_in[5];
  const float* W3 = (const float*)d_in[6];
  const float* b3 = (const float*)d_in[7];
  const float* Wl = (const float*)d_in[8];
  const float* bl = (const float*)d_in[9];
  float* out = (float*)d_out;

  const int nN = in_sizes[0] / NFEAT;   // 100000
  const int nE = in_sizes[1] / 2;       // 1600000
  const int total = nN + nE;
  const int nbkt = (nN + BROW - 1) >> 9;          // 196
  const int nbBin = (total + BINC - 1) / BINC;

  char* ws = (char*)d_ws;
  int*    bkt_cnt = (int*)ws;     ws += alignup(256 * 4);
  int*    bkt_off = (int*)ws;     ws += alignup(257 * 4);
  int*    gfront  = (int*)ws;     ws += alignup(256 * 4);
  int*    row_ptr = (int*)ws;     ws += alignup((size_t)(nN + 1) * 4);
  float*  dis     = (float*)ws;   ws += alignup((size_t)nN * 4);
  float*  Wf      = (float*)ws;   ws += alignup((size_t)NFEAT * NCP * 4);
  float*  bfv     = (float*)ws;   ws += alignup((size_t)NCP * 4);
  ushort* Wt1     = (ushort*)ws;  ws += alignup((size_t)NFEAT * NFEAT * 2);
  ushort* Wt2     = (ushort*)ws;  ws += alignup((size_t)NFEAT * NFEAT * 2);
  int2*   binned  = (int2*)ws;    ws += alignup((size_t)total * 8);
  int*    ev      = (int*)ws;     ws += alignup((size_t)total * 4);
  ushort* hb      = (ushort*)ws;  ws += alignup((size_t)nN * NFEAT * 2);  // gemm out (bf16 rows)
  ushort* hbA     = (ushort*)ws;  ws += alignup((size_t)nN * NFEAT * 2);  // agg out (bf16 rows)
  float*  G       = (float*)ws;   ws += alignup((size_t)nN * NCP * 4);

  // ---- CSR build
  zero_ints<<<1, 256, 0, stream>>>(bkt_cnt, nbkt);
  bucket_hist<<<512, 256, 0, stream>>>(ei + nE, bkt_cnt, nE, nbkt);
  bkt_scan<<<1, 256, 0, stream>>>(bkt_cnt, bkt_off, gfront, nN, nbkt);
  bin_items<<<nbBin, 256, 0, stream>>>(ei, nE, total, nbkt, gfront, binned);
  bucket_finalize<<<nbkt, BROW, 0, stream>>>(binned, bkt_off, row_ptr, dis, ev, nN, nbkt);

  // ---- weight prep
  fold_weights<<<8, 256, 0, stream>>>(W3, Wl, b3, bl, Wf, bfv);
  prep_w<<<64, 256, 0, stream>>>(W1, Wt1);
  prep_w<<<64, 256, 0, stream>>>(W2, Wt2);

  const int gemm_grid = (nN + 63) / 64;
  const int node_grid = (nN + 3) / 4;

  // layer 1
  gemm_mfma<false><<<gemm_grid, 256, 0, stream>>>(x, nullptr, Wt1, dis, hb, nN);
  aggregate<<<node_grid, 256, 0, stream>>>(hb, row_ptr, ev, dis, b1, hbA, 1, nN);
  // layer 2
  gemm_mfma<true><<<gemm_grid, 256, 0, stream>>>(nullptr, hbA, Wt2, dis, hb, nN);
  aggregate<<<node_grid, 256, 0, stream>>>(hb, row_ptr, ev, dis, b2, hbA, 1, nN);
  // layer 3 folded with classifier
  gemm_small<<<(nN + 255) / 256, 256, 0, stream>>>(hbA, Wf, dis, G, nN);
  agg_logits<<<node_grid, 256, 0, stream>>>(G, row_ptr, ev, dis, bfv, out, nN);
}

// Round 9
// 355.587 us; speedup vs baseline: 1.9984x; 1.1252x over previous
//
#include <hip/hip_runtime.h>

#define NFEAT 128
#define NCLS  10
#define NCP   16    // padded class count
#define BROW  512   // rows per bucket
#define BINC  4096  // items per binning chunk

static inline size_t alignup(size_t x) { return (x + 255) & ~size_t(255); }

// bf16 helpers (bit-level, RNE)
__device__ __forceinline__ ushort f2bf(float f) {
  uint x = __float_as_uint(f);
  return (ushort)((x + 0x7fffu + ((x >> 16) & 1u)) >> 16);
}
__device__ __forceinline__ float bf2f(ushort u) {
  return __uint_as_float(((uint)u) << 16);
}

typedef short bf16x8 __attribute__((ext_vector_type(8)));
typedef float f32x4 __attribute__((ext_vector_type(4)));

// ---------------- CSR build (bucketed, write-amplification-free) ----------------

__global__ void zero_ints(int* __restrict__ p, int n) {
  int i = blockIdx.x * 256 + threadIdx.x;
  if (i < n) p[i] = 0;
}

__global__ __launch_bounds__(256) void bucket_hist(const int* __restrict__ dst,
                                                   int* __restrict__ bkt_cnt,
                                                   int e, int nbkt) {
  __shared__ int hist[256];
  for (int t = threadIdx.x; t < nbkt; t += 256) hist[t] = 0;
  __syncthreads();
  int i = blockIdx.x * 256 + threadIdx.x;
  int stride = gridDim.x * 256;
  for (; i < e; i += stride) atomicAdd(&hist[dst[i] >> 9], 1);
  __syncthreads();
  for (int t = threadIdx.x; t < nbkt; t += 256)
    if (hist[t]) atomicAdd(&bkt_cnt[t], hist[t]);
}

__global__ __launch_bounds__(256) void bkt_scan(const int* __restrict__ bkt_cnt,
                                                int* __restrict__ bkt_off,
                                                int* __restrict__ gfrontier,
                                                int n, int nbkt) {
  __shared__ int sbuf[256];
  const int t = threadIdx.x;
  int x = 0;
  if (t < nbkt) {
    int lo = t << 9;
    int nodes = n - lo; if (nodes > BROW) nodes = BROW;
    x = bkt_cnt[t] + nodes;
  }
  sbuf[t] = x;
  __syncthreads();
  for (int off = 1; off < 256; off <<= 1) {
    int v = (t >= off) ? sbuf[t - off] : 0;
    __syncthreads();
    sbuf[t] += v;
    __syncthreads();
  }
  if (t < nbkt) { bkt_off[t] = sbuf[t] - x; gfrontier[t] = sbuf[t] - x; }
  if (t == nbkt - 1) bkt_off[nbkt] = sbuf[t];
}

__global__ __launch_bounds__(256) void bin_items(const int* __restrict__ ei,
                                                 int nE, int total, int nbkt,
                                                 int* __restrict__ gfrontier,
                                                 int2* __restrict__ binned) {
  __shared__ int hist[256];
  __shared__ int loff[256];
  __shared__ int gbase[256];
  __shared__ int sbuf[256];
  __shared__ int2 st[BINC];
  const int t = threadIdx.x;
  const int chunk0 = blockIdx.x * BINC;
  for (int q = t; q < nbkt; q += 256) hist[q] = 0;
  __syncthreads();
  for (int j = t; j < BINC; j += 256) {
    int i = chunk0 + j;
    if (i < total) {
      int d = (i < nE) ? ei[nE + i] : (i - nE);
      atomicAdd(&hist[d >> 9], 1);
    }
  }
  __syncthreads();
  int x = (t < nbkt) ? hist[t] : 0;
  sbuf[t] = x;
  __syncthreads();
  for (int off = 1; off < 256; off <<= 1) {
    int v = (t >= off) ? sbuf[t - off] : 0;
    __syncthreads();
    sbuf[t] += v;
    __syncthreads();
  }
  loff[t] = sbuf[t] - x;
  gbase[t] = (t < nbkt && x > 0) ? atomicAdd(&gfrontier[t], x) : 0;
  __syncthreads();
  hist[t] = loff[t];
  __syncthreads();
  for (int j = t; j < BINC; j += 256) {
    int i = chunk0 + j;
    if (i < total) {
      int s, d;
      if (i < nE) { s = ei[i]; d = ei[nE + i]; }
      else        { s = i - nE; d = s; }
      int p = atomicAdd(&hist[d >> 9], 1);
      st[p] = make_int2(s, d);
    }
  }
  __syncthreads();
  int M = total - chunk0; if (M > BINC) M = BINC;
  for (int j = t; j < M; j += 256) {
    int2 it = st[j];
    int b = it.y >> 9;
    binned[gbase[b] + (j - loff[b])] = it;
  }
}

__global__ __launch_bounds__(512) void bucket_finalize(const int2* __restrict__ binned,
                                                       const int* __restrict__ bkt_off,
                                                       int* __restrict__ row_ptr,
                                                       float* __restrict__ dis,
                                                       int* __restrict__ ev,
                                                       int n, int nbkt) {
  __shared__ int hist[BROW];
  __shared__ int sbuf[BROW];
  __shared__ int pre[BROW];
  __shared__ int front[BROW];
  const int b = blockIdx.x;
  const int t = threadIdx.x;
  const int row0 = b << 9;
  const int beg = bkt_off[b], end = bkt_off[b + 1];
  hist[t] = 0; front[t] = 0;
  __syncthreads();
  for (int j = beg + t; j < end; j += BROW)
    atomicAdd(&hist[binned[j].y - row0], 1);
  __syncthreads();
  const int x = hist[t];
  const int v = row0 + t;
  if (v < n) dis[v] = rsqrtf((float)x);
  sbuf[t] = x;
  __syncthreads();
  for (int off = 1; off < BROW; off <<= 1) {
    int val = (t >= off) ? sbuf[t - off] : 0;
    __syncthreads();
    sbuf[t] += val;
    __syncthreads();
  }
  pre[t] = sbuf[t] - x;
  if (v < n) row_ptr[v] = beg + pre[t];
  if (b == nbkt - 1 && t == 0) row_ptr[n] = end;
  __syncthreads();
  for (int j = beg + t; j < end; j += BROW) {
    int2 it = binned[j];
    int dl = it.y - row0;
    int slot = atomicAdd(&front[dl], 1);
    ev[beg + pre[dl] + slot] = it.x;
  }
}

// ---------------- weight prep ----------------

__global__ __launch_bounds__(256) void fold_weights(const float* __restrict__ W3,
                                                    const float* __restrict__ Wl,
                                                    const float* __restrict__ b3,
                                                    const float* __restrict__ bl,
                                                    float* __restrict__ Wf,
                                                    float* __restrict__ bf) {
  int t = blockIdx.x * blockDim.x + threadIdx.x;
  if (t < NFEAT * NCP) {
    int r = t >> 4, c = t & 15;
    float s = 0.f;
    if (c < NCLS) {
      for (int k = 0; k < NFEAT; ++k) s += W3[r * NFEAT + k] * Wl[k * NCLS + c];
    }
    Wf[t] = s;
  }
  if (t < NCP) {
    float s = 0.f;
    if (t < NCLS) {
      s = bl[t];
      for (int k = 0; k < NFEAT; ++k) s += b3[k] * Wl[k * NCLS + t];
    }
    bf[t] = s;
  }
}

__global__ __launch_bounds__(256) void prep_w(const float* __restrict__ W,
                                              ushort* __restrict__ Wt) {
  int t = blockIdx.x * 256 + threadIdx.x;
  if (t < NFEAT * NFEAT) {
    int n = t >> 7, k = t & 127;
    Wt[n * NFEAT + k] = f2bf(W[k * NFEAT + n]);
  }
}

// ---- MFMA GEMM: Cb[r](bf16 row-major) = dis[r] * (A[r] @ W) ----
// BF16IN=false: A fp32 row-major. BF16IN=true: Ab bf16 row-major.

template<bool BF16IN>
__global__ __launch_bounds__(256) void gemm_mfma(const float* __restrict__ A,
                                                 const ushort* __restrict__ Ab,
                                                 const ushort* __restrict__ Wt,
                                                 const float* __restrict__ dis,
                                                 ushort* __restrict__ Cb, int nrows) {
  __shared__ __align__(16) ushort Asm[64 * NFEAT];   // 16 KB
  const int tid = threadIdx.x;
  const int row0 = blockIdx.x * 64;
  {
    const int m = tid >> 2;
    const int kc = (tid & 3) * 32;
    const int gr = row0 + m;
    int4 u[4];
    if (BF16IN) {
      if (gr < nrows) {
        const ushort* p = Ab + (size_t)gr * NFEAT + kc;
        u[0] = *(const int4*)(p + 0);
        u[1] = *(const int4*)(p + 8);
        u[2] = *(const int4*)(p + 16);
        u[3] = *(const int4*)(p + 24);
      } else {
        u[0] = u[1] = u[2] = u[3] = make_int4(0, 0, 0, 0);
      }
    } else {
      float4 f[8];
      if (gr < nrows) {
        #pragma unroll
        for (int q = 0; q < 8; ++q)
          f[q] = *(const float4*)&A[(size_t)gr * NFEAT + kc + q * 4];
      } else {
        #pragma unroll
        for (int q = 0; q < 8; ++q) f[q] = make_float4(0.f, 0.f, 0.f, 0.f);
      }
      #pragma unroll
      for (int q = 0; q < 4; ++q) {
        union { ushort us[8]; int4 v; } pk;
        const float* fp = (const float*)&f[q * 2];
        #pragma unroll
        for (int j = 0; j < 8; ++j) pk.us[j] = f2bf(fp[j]);
        u[q] = pk.v;
      }
    }
    #pragma unroll
    for (int q = 0; q < 4; ++q) {
      int byte = (m * 256 + (kc + q * 8) * 2) ^ ((m & 7) << 4);
      *(int4*)((char*)Asm + byte) = u[q];
    }
  }
  __syncthreads();
  const int wave = tid >> 6;
  const int lane = tid & 63;
  const int m0 = wave * 16;
  bf16x8 afr[4];
  #pragma unroll
  for (int ks = 0; ks < 4; ++ks) {
    int m = m0 + (lane & 15);
    int kk = ks * 32 + (lane >> 4) * 8;
    int byte = (m * 256 + kk * 2) ^ ((m & 7) << 4);
    afr[ks] = *(const bf16x8*)((const char*)Asm + byte);
  }
  f32x4 acc[8];
  #pragma unroll
  for (int c = 0; c < 8; ++c) acc[c] = (f32x4){0.f, 0.f, 0.f, 0.f};
  #pragma unroll
  for (int c = 0; c < 8; ++c) {
    #pragma unroll
    for (int ks = 0; ks < 4; ++ks) {
      int n = c * 16 + (lane & 15);
      int kk = ks * 32 + (lane >> 4) * 8;
      bf16x8 bfr = *(const bf16x8*)&Wt[n * NFEAT + kk];
      acc[c] = __builtin_amdgcn_mfma_f32_16x16x32_bf16(afr[ks], bfr, acc[c], 0, 0, 0);
    }
  }
  const int gr_base = row0 + m0 + (lane >> 4) * 4;
  float dr[4];
  #pragma unroll
  for (int r = 0; r < 4; ++r)
    dr[r] = (gr_base + r < nrows) ? dis[gr_base + r] : 0.f;
  #pragma unroll
  for (int c = 0; c < 8; ++c) {
    #pragma unroll
    for (int r = 0; r < 4; ++r) {
      int gr = gr_base + r;
      if (gr < nrows)
        Cb[(size_t)gr * NFEAT + c * 16 + (lane & 15)] = f2bf(acc[c][r] * dr[r]);
    }
  }
}

// ------- sparse aggregation: outb[v] = bf16(relu?(dis[v]*Σ h'[src] + bias)) -------
// round-6 loop shape: half-wave ushort4, 4 edges/half/iter -> 8 gathers in flight,
// plain cached ev loads (broadcast-reused across the half-wave).

__global__ __launch_bounds__(256) void aggregate(const ushort* __restrict__ hw,
                                                 const int* __restrict__ row_ptr,
                                                 const int* __restrict__ ev,
                                                 const float* __restrict__ dis,
                                                 const float* __restrict__ bias,
                                                 ushort* __restrict__ outb,
                                                 int relu, int n) {
  const int wave = threadIdx.x >> 6;
  const int lane = threadIdx.x & 63;
  const int v = blockIdx.x * 4 + wave;
  if (v >= n) return;
  const int beg = row_ptr[v], end = row_ptr[v + 1];
  const int half = lane >> 5;        // 0/1: edge parity handled by this half-wave
  const int hl = lane & 31;          // feature group: feats hl*4 .. hl*4+3
  float4 acc = make_float4(0.f, 0.f, 0.f, 0.f);
  int e = beg + half;
  for (; e + 6 < end; e += 8) {      // 4 edges per half per iter -> 8 gathers in flight
    int s0 = ev[e];
    int s1 = ev[e + 2];
    int s2 = ev[e + 4];
    int s3 = ev[e + 6];
    ushort4 q0 = *(const ushort4*)&hw[(size_t)s0 * NFEAT + hl * 4];
    ushort4 q1 = *(const ushort4*)&hw[(size_t)s1 * NFEAT + hl * 4];
    ushort4 q2 = *(const ushort4*)&hw[(size_t)s2 * NFEAT + hl * 4];
    ushort4 q3 = *(const ushort4*)&hw[(size_t)s3 * NFEAT + hl * 4];
    acc.x += bf2f(q0.x) + bf2f(q1.x) + bf2f(q2.x) + bf2f(q3.x);
    acc.y += bf2f(q0.y) + bf2f(q1.y) + bf2f(q2.y) + bf2f(q3.y);
    acc.z += bf2f(q0.z) + bf2f(q1.z) + bf2f(q2.z) + bf2f(q3.z);
    acc.w += bf2f(q0.w) + bf2f(q1.w) + bf2f(q2.w) + bf2f(q3.w);
  }
  for (; e < end; e += 2) {
    int s = ev[e];
    ushort4 q = *(const ushort4*)&hw[(size_t)s * NFEAT + hl * 4];
    acc.x += bf2f(q.x); acc.y += bf2f(q.y);
    acc.z += bf2f(q.z); acc.w += bf2f(q.w);
  }
  acc.x += __shfl_xor(acc.x, 32);
  acc.y += __shfl_xor(acc.y, 32);
  acc.z += __shfl_xor(acc.z, 32);
  acc.w += __shfl_xor(acc.w, 32);
  if (half == 0) {
    float dv = dis[v];
    float4 b = *(const float4*)&bias[hl * 4];
    acc.x = fmaf(acc.x, dv, b.x); acc.y = fmaf(acc.y, dv, b.y);
    acc.z = fmaf(acc.z, dv, b.z); acc.w = fmaf(acc.w, dv, b.w);
    if (relu) {
      acc.x = fmaxf(acc.x, 0.f); acc.y = fmaxf(acc.y, 0.f);
      acc.z = fmaxf(acc.z, 0.f); acc.w = fmaxf(acc.w, 0.f);
    }
    union { ushort us[4]; uint2 q2; } pk;
    pk.us[0] = f2bf(acc.x); pk.us[1] = f2bf(acc.y);
    pk.us[2] = f2bf(acc.z); pk.us[3] = f2bf(acc.w);
    *(uint2*)&outb[(size_t)v * NFEAT + hl * 4] = pk.q2;
  }
}

// ---- thin GEMM: G[v][16](fp32) = dis[v] * (Ab[v] @ Wf), Ab bf16 row-major ----

__global__ __launch_bounds__(256) void gemm_small(const ushort* __restrict__ Ab,
                                                  const float* __restrict__ Wf,
                                                  const float* __restrict__ dis,
                                                  float* __restrict__ G, int n) {
  __shared__ float Ws[NFEAT * NCP];  // 8 KB
  for (int i = threadIdx.x; i < NFEAT * NCP; i += 256) Ws[i] = Wf[i];
  __syncthreads();
  const int v = blockIdx.x * 256 + threadIdx.x;
  if (v >= n) return;
  float acc[NCP];
  #pragma unroll
  for (int c = 0; c < NCP; ++c) acc[c] = 0.f;
  #pragma unroll
  for (int p = 0; p < 8; ++p) {
    union { ushort us[16]; int4 q[2]; } a;
    const ushort* pl = Ab + (size_t)v * NFEAT + p * 16;
    a.q[0] = *(const int4*)pl;
    a.q[1] = *(const int4*)(pl + 8);
    #pragma unroll
    for (int j = 0; j < 16; ++j) {
      float av = bf2f(a.us[j]);
      int k = p * 16 + j;
      #pragma unroll
      for (int cq = 0; cq < NCP; cq += 4) {
        float4 w = *(const float4*)&Ws[k * NCP + cq];
        acc[cq + 0] += av * w.x;
        acc[cq + 1] += av * w.y;
        acc[cq + 2] += av * w.z;
        acc[cq + 3] += av * w.w;
      }
    }
  }
  const float dv = dis[v];
  #pragma unroll
  for (int cq = 0; cq < NCP; cq += 4)
    *(float4*)&G[(size_t)v * NCP + cq] =
        make_float4(acc[cq] * dv, acc[cq + 1] * dv, acc[cq + 2] * dv, acc[cq + 3] * dv);
}

// ---------------- fused aggregation (16 feats) + bias + log_softmax ----------------

__global__ __launch_bounds__(256) void agg_logits(const float* __restrict__ G,
                                                  const int* __restrict__ row_ptr,
                                                  const int* __restrict__ ev,
                                                  const float* __restrict__ dis,
                                                  const float* __restrict__ bf,
                                                  float* __restrict__ out, int n) {
  const int wave = threadIdx.x >> 6;
  const int lane = threadIdx.x & 63;
  const int v = blockIdx.x * 4 + wave;
  if (v >= n) return;
  const int beg = row_ptr[v], end = row_ptr[v + 1];
  const int g = lane >> 4;           // 4 edge groups
  const int f = lane & 15;           // feature (class) index
  float acc = 0.f;
  int e = beg + g;
  for (; e + 4 < end; e += 8) {
    int s0 = ev[e];
    int s1 = ev[e + 4];
    acc += G[(size_t)s0 * NCP + f] + G[(size_t)s1 * NCP + f];
  }
  for (; e < end; e += 4) {
    acc += G[(size_t)ev[e] * NCP + f];
  }
  acc += __shfl_xor(acc, 16);
  acc += __shfl_xor(acc, 32);
  float logit = dis[v] * acc + bf[f];
  float pv = (f < NCLS) ? logit : -INFINITY;
  float m = pv;
  #pragma unroll
  for (int s = 8; s >= 1; s >>= 1) m = fmaxf(m, __shfl_xor(m, s));
  float ex = (f < NCLS) ? expf(logit - m) : 0.f;
  float ssum = ex;
  #pragma unroll
  for (int s = 8; s >= 1; s >>= 1) ssum += __shfl_xor(ssum, s);
  float lse = m + logf(ssum);
  if (g == 0 && f < NCLS) out[(size_t)v * NCLS + f] = logit - lse;
}

// ---------------- launcher ----------------

extern "C" void kernel_launch(void* const* d_in, const int* in_sizes, int n_in,
                              void* d_out, int out_size, void* d_ws, size_t ws_size,
                              hipStream_t stream) {
  const float* x  = (const float*)d_in[0];
  const int*   ei = (const int*)d_in[1];
  const float* W1 = (const float*)d_in[2];
  const float* b1 = (const float*)d_in[3];
  const float* W2 = (const float*)d_in[4];
  const float* b2 = (const float*)d_in[5];
  const float* W3 = (const float*)d_in[6];
  const float* b3 = (const float*)d_in[7];
  const float* Wl = (const float*)d_in[8];
  const float* bl = (const float*)d_in[9];
  float* out = (float*)d_out;

  const int nN = in_sizes[0] / NFEAT;   // 100000
  const int nE = in_sizes[1] / 2;       // 1600000
  const int total = nN + nE;
  const int nbkt = (nN + BROW - 1) >> 9;          // 196
  const int nbBin = (total + BINC - 1) / BINC;

  char* ws = (char*)d_ws;
  int*    bkt_cnt = (int*)ws;     ws += alignup(256 * 4);
  int*    bkt_off = (int*)ws;     ws += alignup(257 * 4);
  int*    gfront  = (int*)ws;     ws += alignup(256 * 4);
  int*    row_ptr = (int*)ws;     ws += alignup((size_t)(nN + 1) * 4);
  float*  dis     = (float*)ws;   ws += alignup((size_t)nN * 4);
  float*  Wf      = (float*)ws;   ws += alignup((size_t)NFEAT * NCP * 4);
  float*  bfv     = (float*)ws;   ws += alignup((size_t)NCP * 4);
  ushort* Wt1     = (ushort*)ws;  ws += alignup((size_t)NFEAT * NFEAT * 2);
  ushort* Wt2     = (ushort*)ws;  ws += alignup((size_t)NFEAT * NFEAT * 2);
  int2*   binned  = (int2*)ws;    ws += alignup((size_t)total * 8);
  int*    ev      = (int*)ws;     ws += alignup((size_t)total * 4);
  ushort* hb      = (ushort*)ws;  ws += alignup((size_t)nN * NFEAT * 2);  // gemm out (bf16 rows)
  ushort* hbA     = (ushort*)ws;  ws += alignup((size_t)nN * NFEAT * 2);  // agg out (bf16 rows)
  float*  G       = (float*)ws;   ws += alignup((size_t)nN * NCP * 4);

  // ---- CSR build
  zero_ints<<<1, 256, 0, stream>>>(bkt_cnt, nbkt);
  bucket_hist<<<512, 256, 0, stream>>>(ei + nE, bkt_cnt, nE, nbkt);
  bkt_scan<<<1, 256, 0, stream>>>(bkt_cnt, bkt_off, gfront, nN, nbkt);
  bin_items<<<nbBin, 256, 0, stream>>>(ei, nE, total, nbkt, gfront, binned);
  bucket_finalize<<<nbkt, BROW, 0, stream>>>(binned, bkt_off, row_ptr, dis, ev, nN, nbkt);

  // ---- weight prep
  fold_weights<<<8, 256, 0, stream>>>(W3, Wl, b3, bl, Wf, bfv);
  prep_w<<<64, 256, 0, stream>>>(W1, Wt1);
  prep_w<<<64, 256, 0, stream>>>(W2, Wt2);

  const int gemm_grid = (nN + 63) / 64;
  const int node_grid = (nN + 3) / 4;

  // layer 1
  gemm_mfma<false><<<gemm_grid, 256, 0, stream>>>(x, nullptr, Wt1, dis, hb, nN);
  aggregate<<<node_grid, 256, 0, stream>>>(hb, row_ptr, ev, dis, b1, hbA, 1, nN);
  // layer 2
  gemm_mfma<true><<<gemm_grid, 256, 0, stream>>>(nullptr, hbA, Wt2, dis, hb, nN);
  aggregate<<<node_grid, 256, 0, stream>>>(hb, row_ptr, ev, dis, b2, hbA, 1, nN);
  // layer 3 folded with classifier
  gemm_small<<<(nN + 255) / 256, 256, 0, stream>>>(hbA, Wf, dis, G, nN);
  agg_logits<<<node_grid, 256, 0, stream>>>(G, row_ptr, ev, dis, bfv, out, nN);
}